// Round 19
// baseline (216.568 us; speedup 1.0000x reference)
//
#include <hip/hip_runtime.h>

// ---------------------------------------------------------------------------
// Fused QKV-projection + attention (B=8, C=2048, N=512), fp32 in/out.
// Round 19: FUSED ONLINE SOFTMAX INTO S-GEMM. R18's S made a 200 MB/chunk
// fp32 round-trip just to find row maxes. Now s_softmax blocks own 64 c-rows
// x a 1024-kv d-half (q panel 64KB staged once; k 2-phase dbuf) and emit
// P' = exp(S - m_t) fp16 + per-tile m_t + per-half (m,l) online. sm_merge
// (64 blocks) joins halves. pv_gemm reg-stages A with sc=exp(m_t - m_glob)
// from LDS (write-side swizzle == old read side), B keeps global_load_lds.
// No chunking (P' fp16 = 67 MB fits ws/L3). Casts merged. 14 -> 7 launches.
// Predicted absmax ~3.4e-3 (one extra fp16 rounding on P), thr 4.57e-3.
// ---------------------------------------------------------------------------

typedef _Float16 half_t;
typedef __attribute__((ext_vector_type(8))) _Float16 half8;
typedef __attribute__((ext_vector_type(4))) _Float16 half4;
typedef __attribute__((ext_vector_type(4))) float    f32x4;

#define MFMA16x32(A_, B_, C_) __builtin_amdgcn_mfma_f32_16x16x32_f16((A_), (B_), (C_), 0, 0, 0)

__device__ __forceinline__ void gload_lds16(const void* g, void* l) {
  __builtin_amdgcn_global_load_lds(
      (const __attribute__((address_space(1))) void*)g,
      (__attribute__((address_space(3))) void*)l, 16, 0, 0);
}

// max-reduce over each 16-lane group via DPP (validated R7+).
__device__ __forceinline__ float dpp_max16(float x) {
  int t;
  t = __builtin_amdgcn_update_dpp(__float_as_int(x), __float_as_int(x), 0xB1, 0xF, 0xF, false);
  x = fmaxf(x, __int_as_float(t));
  t = __builtin_amdgcn_update_dpp(__float_as_int(x), __float_as_int(x), 0x4E, 0xF, 0xF, false);
  x = fmaxf(x, __int_as_float(t));
  t = __builtin_amdgcn_update_dpp(__float_as_int(x), __float_as_int(x), 0x124, 0xF, 0xF, false);
  x = fmaxf(x, __int_as_float(t));
  t = __builtin_amdgcn_update_dpp(__float_as_int(x), __float_as_int(x), 0x128, 0xF, 0xF, false);
  x = fmaxf(x, __int_as_float(t));
  return x;
}

__device__ __forceinline__ float dpp_sum16(float x) {
  int t;
  t = __builtin_amdgcn_update_dpp(__float_as_int(x), __float_as_int(x), 0xB1, 0xF, 0xF, false);
  x += __int_as_float(t);
  t = __builtin_amdgcn_update_dpp(__float_as_int(x), __float_as_int(x), 0x4E, 0xF, 0xF, false);
  x += __int_as_float(t);
  t = __builtin_amdgcn_update_dpp(__float_as_int(x), __float_as_int(x), 0x124, 0xF, 0xF, false);
  x += __int_as_float(t);
  t = __builtin_amdgcn_update_dpp(__float_as_int(x), __float_as_int(x), 0x128, 0xF, 0xF, false);
  x += __int_as_float(t);
  return x;
}

// ---- merged cast: x + Wq + Wk + Wv in one launch ----------------------------
__global__ void cast_all(const float* __restrict__ x, const float* __restrict__ Wq,
                         const float* __restrict__ Wk, const float* __restrict__ Wv,
                         half_t* __restrict__ xh, half_t* __restrict__ wqh,
                         half_t* __restrict__ wkh, half_t* __restrict__ wvh) {
  int idx = blockIdx.x * 256 + threadIdx.x;   // float4 index
  const float* s;
  half_t* d;
  int off;
  if (idx < 2097152) { s = x; d = xh; off = idx; }
  else {
    int w = idx - 2097152;
    int which = w >> 16;
    off = w & 65535;
    s = (which == 0) ? Wq : (which == 1) ? Wk : Wv;
    d = (which == 0) ? wqh : (which == 1) ? wkh : wvh;
  }
  f32x4 v = ((const f32x4*)s)[off];
  half4 h;
#pragma unroll
  for (int j = 0; j < 4; ++j) h[j] = (_Float16)v[j];
  *(half4*)&d[(size_t)off * 4] = h;
}

// ---- GEMM core for projections (unchanged from R18, MR=4) -------------------
template <int NKT, int SA, int SB, int MR>
__device__ __forceinline__ void gemm_core(
    const char* Abytes, const char* Bbytes,
    half_t* At, half_t* Bt, int tid, f32x4 (&acc)[MR][4]) {
  const int lane = tid & 63;
  const int wv = tid >> 6;
  const int g = lane >> 4, li = lane & 15;
  const int wm = wv >> 1, wn = wv & 1;
  const int ASTRIDE = MR * 2048;

  auto STAGE = [&](int kc, int buf) {
#pragma unroll
    for (int i2 = 0; i2 < MR; ++i2) {
      int seg = i2 * 256 + tid;
      int row = seg >> 3, blk = seg & 7;
      int bsrc = blk ^ (row & 7);
      gload_lds16(Abytes + ((size_t)row * SA + kc + bsrc * 8) * 2,
                  (void*)&At[buf * ASTRIDE + seg * 8]);
    }
#pragma unroll
    for (int i2 = 0; i2 < 4; ++i2) {
      int seg = i2 * 256 + tid;
      int row = seg >> 3, blk = seg & 7;
      int bsrc = blk ^ (row & 7);
      gload_lds16(Bbytes + ((size_t)row * SB + kc + bsrc * 8) * 2,
                  (void*)&Bt[buf * 8192 + seg * 8]);
    }
  };

  STAGE(0, 0);
  __syncthreads();
  int cur = 0;
#pragma unroll 1
  for (int kt = 0; kt < NKT; ++kt) {
    if (kt + 1 < NKT) STAGE((kt + 1) * 64, cur ^ 1);
#pragma unroll
    for (int kk = 0; kk < 2; ++kk) {
      half8 af[MR], bf[4];
#pragma unroll
      for (int i = 0; i < MR; ++i) {
        int ar = wm * (MR * 16) + i * 16 + li;
        af[i] = *(const half8*)&At[cur * ASTRIDE + ar * 64 + (((4 * kk + g) ^ (ar & 7)) * 8)];
      }
#pragma unroll
      for (int j = 0; j < 4; ++j) {
        int br = wn * 64 + j * 16 + li;
        bf[j] = *(const half8*)&Bt[cur * 8192 + br * 64 + (((4 * kk + g) ^ (br & 7)) * 8)];
      }
#pragma unroll
      for (int i = 0; i < MR; ++i)
#pragma unroll
        for (int j = 0; j < 4; ++j) acc[i][j] = MFMA16x32(af[i], bf[j], acc[i][j]);
    }
    __syncthreads();
    cur ^= 1;
  }
}

// ---- projection GEMM (unchanged) --------------------------------------------
// MODE 2: out[t*512 + m] (q/k compact); MODE 1: out[m*16384 + t] (v transposed)
template <int MODE>
__global__ __launch_bounds__(256) void proj_gemm(
    const half_t* __restrict__ A, const half_t* __restrict__ Bm,
    const float* __restrict__ bias, half_t* __restrict__ out) {
  __shared__ half_t At[2 * 4 * 2048];
  __shared__ half_t Bt[2 * 8192];
  const int tid = threadIdx.x;
  const int lane = tid & 63, wv = tid >> 6;
  const int g = lane >> 4, li = lane & 15;
  const int wm = wv >> 1, wn = wv & 1;
  const int M0 = blockIdx.x * 128, N0 = blockIdx.y * 128;

  const f32x4 kZero = {0.f, 0.f, 0.f, 0.f};
  f32x4 acc[4][4];
#pragma unroll
  for (int i = 0; i < 4; ++i)
#pragma unroll
    for (int j = 0; j < 4; ++j) acc[i][j] = kZero;

  gemm_core<8, 512, 512, 4>((const char*)(A + (size_t)M0 * 512),
                            (const char*)(Bm + (size_t)N0 * 512), At, Bt, tid, acc);

  if (MODE == 2) {
#pragma unroll
    for (int i = 0; i < 4; ++i) {
      int trow = M0 + wm * 64 + i * 16 + 4 * g;
#pragma unroll
      for (int j = 0; j < 4; ++j) {
        int m = N0 + wn * 64 + j * 16 + li;
        float bs = bias[m];
#pragma unroll
        for (int r = 0; r < 4; ++r) {
          out[(size_t)(trow + r) * 512 + m] = (_Float16)(acc[i][j][r] + bs);
        }
      }
    }
  } else {
#pragma unroll
    for (int i = 0; i < 4; ++i) {
      int m0r = M0 + wm * 64 + i * 16 + 4 * g;
#pragma unroll
      for (int r = 0; r < 4; ++r) {
        int m = m0r + r;
        float bs = bias[m];
#pragma unroll
        for (int j = 0; j < 4; ++j) {
          int t = N0 + wn * 64 + j * 16 + li;
          out[(size_t)m * 16384 + t] = (_Float16)(acc[i][j][r] + bs);
        }
      }
    }
  }
}

// ---- fused S-GEMM + online softmax ------------------------------------------
// grid 512: b = id&7 (XCD affinity); rest = id>>3: M0 = (rest>>1)*64 (c-rows),
// h = rest&1 (d-half, 1024 kv). q panel (64x512 = 64 KB) staged once; k tiles
// (64 d x 64 k = 8 KB) 2-phase dbuf, 128 steps. After each 64-wide d-tile:
// wave-local DPP row-max, online (m,l) update, P' = exp(S - m_t) fp16 out,
// m_t[row][htile] out. End: per-half m_fin/l_h.
__global__ __launch_bounds__(256) void s_softmax(
    const half_t* __restrict__ q, const half_t* __restrict__ k,
    half_t* __restrict__ Pp, float* __restrict__ m_t,
    float* __restrict__ m_fin, float* __restrict__ l_h) {
  __shared__ half_t At[64 * 512];      // 64 KB q panel
  __shared__ half_t Bt[2][64 * 64];    // 2 x 8 KB k tiles
  const int tid = threadIdx.x;
  const int lane = tid & 63, wv = tid >> 6;
  const int g = lane >> 4, li = lane & 15;
  const int id = blockIdx.x;
  const int b = id & 7;
  const int rest = id >> 3;
  const int M0 = (rest >> 1) * 64;
  const int h = rest & 1;
  const int d0 = h * 1024;

  const char* qb = (const char*)(q + (size_t)(b * 2048 + M0) * 512);
  const char* kb = (const char*)(k + (size_t)(b * 2048 + d0) * 512);

  // stage q panel once: 4096 16B segs, 16/thread; swizzle within 8-blk stripes
#pragma unroll
  for (int i2 = 0; i2 < 16; ++i2) {
    int seg = i2 * 256 + tid;
    int row = seg >> 6, blk = seg & 63;
    int bsrc = blk ^ (row & 7);
    gload_lds16(qb + ((size_t)row * 512 + bsrc * 8) * 2, (void*)&At[seg * 8]);
  }

  auto BSTAGE = [&](int it, int buf) {   // it = dt*8 + ks
    int dt = it >> 3, ks = it & 7;
#pragma unroll
    for (int i2 = 0; i2 < 2; ++i2) {
      int seg = i2 * 256 + tid;
      int row = seg >> 3, blk = seg & 7;
      int bsrc = blk ^ (row & 7);
      gload_lds16(kb + ((size_t)(dt * 64 + row) * 512 + ks * 64 + bsrc * 8) * 2,
                  (void*)&Bt[buf][seg * 8]);
    }
  };
  BSTAGE(0, 0);
  __syncthreads();

  const int ar = wv * 16 + li;         // this lane's A row (within 64)
  const int swzA = ar & 7;
  const f32x4 kZero = {0.f, 0.f, 0.f, 0.f};
  float m_run[4] = {-3e38f, -3e38f, -3e38f, -3e38f};
  float l_run[4] = {0.f, 0.f, 0.f, 0.f};
  f32x4 acc[4];
  int cur = 0;

#pragma unroll 1
  for (int it = 0; it < 128; ++it) {
    const int dt = it >> 3, ks = it & 7;
    if (ks == 0) {
#pragma unroll
      for (int j = 0; j < 4; ++j) acc[j] = kZero;
    }
    if (it + 1 < 128) BSTAGE(it + 1, cur ^ 1);

#pragma unroll
    for (int kk = 0; kk < 2; ++kk) {
      half8 af = *(const half8*)&At[ar * 512 + (((ks * 8 + kk * 4 + g) ^ swzA) * 8)];
#pragma unroll
      for (int j = 0; j < 4; ++j) {
        int br = j * 16 + li;
        half8 bf = *(const half8*)&Bt[cur][br * 64 + (((kk * 4 + g) ^ (br & 7)) * 8)];
        acc[j] = MFMA16x32(af, bf, acc[j]);
      }
    }

    if (ks == 7) {   // tile dt complete: online softmax (register+DPP only)
      float mnew[4], alpha[4], tsum[4];
#pragma unroll
      for (int r = 0; r < 4; ++r) {
        float tm = fmaxf(fmaxf(acc[0][r], acc[1][r]), fmaxf(acc[2][r], acc[3][r]));
        tm = dpp_max16(tm);
        mnew[r] = fmaxf(m_run[r], tm);
        alpha[r] = __expf(m_run[r] - mnew[r]);
        tsum[r] = 0.f;
      }
      // P' = exp(S - mnew) <= 1, write fp16; accumulate tile sums
      const size_t prow0 = (size_t)(b * 2048 + M0 + wv * 16);
#pragma unroll
      for (int j = 0; j < 4; ++j) {
#pragma unroll
        for (int r = 0; r < 4; ++r) {
          float p = __expf(acc[j][r] - mnew[r]);
          tsum[r] += p;
          Pp[(prow0 + 4 * g + r) * 2048 + d0 + dt * 64 + j * 16 + li] = (_Float16)p;
        }
      }
#pragma unroll
      for (int r = 0; r < 4; ++r) {
        float ts = dpp_sum16(tsum[r]);
        l_run[r] = l_run[r] * alpha[r] + ts;
        m_run[r] = mnew[r];
      }
      if (li == 0) {
#pragma unroll
        for (int r = 0; r < 4; ++r)
          m_t[(prow0 + 4 * g + r) * 32 + h * 16 + dt] = mnew[r];
      }
    }

    __syncthreads();   // protect Bt[cur^1] overwrite next iteration
    cur ^= 1;
  }

  if (li == 0) {
    const size_t prow0 = (size_t)(b * 2048 + M0 + wv * 16);
#pragma unroll
    for (int r = 0; r < 4; ++r) {
      m_fin[(prow0 + 4 * g + r) * 2 + h] = m_run[r];
      l_h[(prow0 + 4 * g + r) * 2 + h] = l_run[r];
    }
  }
}

// ---- merge the two d-halves' (m, l) -----------------------------------------
__global__ void sm_merge(const float* __restrict__ m_fin, const float* __restrict__ l_h,
                         float* __restrict__ m_glob, float* __restrict__ l_fin) {
  int rr = blockIdx.x * 256 + threadIdx.x;   // 0..16383
  float m0 = m_fin[rr * 2], m1 = m_fin[rr * 2 + 1];
  float mg = fmaxf(m0, m1);
  l_fin[rr] = l_h[rr * 2] * __expf(m0 - mg) + l_h[rr * 2 + 1] * __expf(m1 - mg);
  m_glob[rr] = mg;
}

// ---- PV-GEMM (M=64): out[b][n][c] = (P . V^T) / (l * sqrt512) ---------------
// grid 1024: b = id&7; idx = id>>3: M0 = (idx>>2)*64 (c), N0 = (idx&3)*128 (n).
// A reg-staged from P' with per-(row,kt) scale sc = exp(m_t - m_glob) (LDS);
// write-side XOR swizzle == read side. B via global_load_lds (unchanged).
__global__ __launch_bounds__(256) void pv_gemm(
    const half_t* __restrict__ Pp, const half_t* __restrict__ vt,
    const float* __restrict__ m_t, const float* __restrict__ m_glob,
    const float* __restrict__ l_fin, float* __restrict__ outp) {
  __shared__ half_t At[2][2 * 2048];   // 2 x 8 KB (64 rows x 64 halves)
  __shared__ half_t Bt[2][8192];       // 2 x 16 KB (128 rows x 64)
  __shared__ float  sc[64][33];        // per-(row,kt) A scale, padded
  const int tid = threadIdx.x;
  const int lane = tid & 63, wv = tid >> 6;
  const int g = lane >> 4, li = lane & 15;
  const int wm = wv >> 1, wn = wv & 1;
  const int id = blockIdx.x;
  const int b = id & 7;
  const int idx = id >> 3;
  const int M0 = (idx >> 2) * 64;      // c within batch
  const int N0 = (idx & 3) * 128;      // n
  const int rgb = b * 2048 + M0;

  // scales -> LDS (2048 entries, 8/thread)
#pragma unroll
  for (int i2 = 0; i2 < 8; ++i2) {
    int e = i2 * 256 + tid;
    int row = e >> 5, kt = e & 31;
    sc[row][kt] = __expf(m_t[(size_t)(rgb + row) * 32 + kt] - m_glob[rgb + row]);
  }

  const half_t* Pb = Pp + (size_t)rgb * 2048;
  const char* Bb = (const char*)(vt + (size_t)N0 * 16384 + (size_t)b * 2048);

  auto BSTAGE = [&](int kt, int buf) {
#pragma unroll
    for (int i2 = 0; i2 < 4; ++i2) {
      int seg = i2 * 256 + tid;
      int row = seg >> 3, blk = seg & 7;
      int bsrc = blk ^ (row & 7);
      gload_lds16(Bb + ((size_t)row * 16384 + kt * 64 + bsrc * 8) * 2,
                  (void*)&Bt[buf][seg * 8]);
    }
  };
  // A stage (reg): thread handles 2 segs of the 64x64 tile
  const int s0row = tid >> 3, s0blk = tid & 7;          // seg = tid
  const int s1row = (256 + tid) >> 3, s1blk = tid & 7;  // seg = 256+tid

  __syncthreads();   // sc visible

  // prologue: stage kt=0 (A regs->LDS + B gload)
  half8 a0 = *(const half8*)&Pb[(size_t)s0row * 2048 + s0blk * 8];
  half8 a1 = *(const half8*)&Pb[(size_t)s1row * 2048 + s1blk * 8];
  BSTAGE(0, 0);
  {
    _Float16 f0 = (_Float16)sc[s0row][0], f1 = (_Float16)sc[s1row][0];
#pragma unroll
    for (int e = 0; e < 8; ++e) { a0[e] *= f0; a1[e] *= f1; }
    *(half8*)&At[0][s0row * 64 + ((s0blk ^ (s0row & 7)) * 8)] = a0;
    *(half8*)&At[0][s1row * 64 + ((s1blk ^ (s1row & 7)) * 8)] = a1;
  }
  __syncthreads();

  const f32x4 kZero = {0.f, 0.f, 0.f, 0.f};
  f32x4 acc[2][4];
#pragma unroll
  for (int i = 0; i < 2; ++i)
#pragma unroll
    for (int j = 0; j < 4; ++j) acc[i][j] = kZero;

  int cur = 0;
#pragma unroll 1
  for (int kt = 0; kt < 32; ++kt) {
    half8 n0, n1;
    if (kt + 1 < 32) {   // issue next A loads + B gload early (T14 spirit)
      n0 = *(const half8*)&Pb[(size_t)s0row * 2048 + (kt + 1) * 64 + s0blk * 8];
      n1 = *(const half8*)&Pb[(size_t)s1row * 2048 + (kt + 1) * 64 + s1blk * 8];
      BSTAGE(kt + 1, cur ^ 1);
    }
    // compute current
#pragma unroll
    for (int kk = 0; kk < 2; ++kk) {
      half8 af[2], bf[4];
#pragma unroll
      for (int i = 0; i < 2; ++i) {
        int arr = wm * 32 + i * 16 + li;
        af[i] = *(const half8*)&At[cur][arr * 64 + (((4 * kk + g) ^ (arr & 7)) * 8)];
      }
#pragma unroll
      for (int j = 0; j < 4; ++j) {
        int br = wn * 64 + j * 16 + li;
        bf[j] = *(const half8*)&Bt[cur][br * 64 + (((4 * kk + g) ^ (br & 7)) * 8)];
      }
#pragma unroll
      for (int i = 0; i < 2; ++i)
#pragma unroll
        for (int j = 0; j < 4; ++j) acc[i][j] = MFMA16x32(af[i], bf[j], acc[i][j]);
    }
    if (kt + 1 < 32) {   // scale + write next A tile into the other buffer
      _Float16 f0 = (_Float16)sc[s0row][kt + 1], f1 = (_Float16)sc[s1row][kt + 1];
#pragma unroll
      for (int e = 0; e < 8; ++e) { n0[e] *= f0; n1[e] *= f1; }
      *(half8*)&At[cur ^ 1][s0row * 64 + ((s0blk ^ (s0row & 7)) * 8)] = n0;
      *(half8*)&At[cur ^ 1][s1row * 64 + ((s1blk ^ (s1row & 7)) * 8)] = n1;
    }
    __syncthreads();
    cur ^= 1;
  }

  // epilogue: 1/(l*sqrt(512)), transposed scatter out[b][n][c]
#pragma unroll
  for (int i = 0; i < 2; ++i) {
    int c0r = M0 + wm * 32 + i * 16 + 4 * g;
    float inv[4];
#pragma unroll
    for (int r = 0; r < 4; ++r)
      inv[r] = 1.0f / (l_fin[b * 2048 + c0r + r] * 22.62741699796952f);
#pragma unroll
    for (int j = 0; j < 4; ++j) {
      int n = N0 + wn * 64 + j * 16 + li;
      float* ob = outp + (size_t)b * 1048576 + (size_t)n * 2048 + c0r;
#pragma unroll
      for (int r = 0; r < 4; ++r) {
        ob[r] = acc[i][j][r] * inv[r];
      }
    }
  }
}

// ---------------------------------------------------------------------------
extern "C" void kernel_launch(void* const* d_in, const int* in_sizes, int n_in,
                              void* d_out, int out_size, void* d_ws, size_t ws_size,
                              hipStream_t stream) {
  const float* x  = (const float*)d_in[0];
  const float* Wq = (const float*)d_in[1];
  const float* bq = (const float*)d_in[2];
  const float* Wk = (const float*)d_in[3];
  const float* bk = (const float*)d_in[4];
  const float* Wv = (const float*)d_in[5];
  const float* bv = (const float*)d_in[6];

  // workspace layout:
  half_t* qsb  = (half_t*)d_ws;                     // [16384][512]   16 MB
  half_t* ksb  = qsb + (size_t)16384 * 512;         // [16384][512]   16 MB
  half_t* vtb  = ksb + (size_t)16384 * 512;         // [512][16384]   16 MB
  half_t* Pp   = vtb + (size_t)512 * 16384;         // [16384][2048]  67 MB (attn)
  half_t* xh   = Pp;                                // [16384][512]   16 MB (proj phase)
  half_t* wqh  = xh  + (size_t)16384 * 512;         // [512][512]
  half_t* wkh  = wqh + (size_t)512 * 512;
  half_t* wvh  = wkh + (size_t)512 * 512;
  float*  m_t  = (float*)(Pp + (size_t)16384 * 2048);   // [16384][32]  2 MB
  float*  m_fin = m_t + (size_t)16384 * 32;             // [16384][2]
  float*  l_hb  = m_fin + (size_t)16384 * 2;            // [16384][2]
  float*  m_glb = l_hb + (size_t)16384 * 2;             // [16384]
  float*  l_fin = m_glb + (size_t)16384;                // [16384]

  cast_all<<<dim3(8960), 256, 0, stream>>>(x, Wq, Wk, Wv, xh, wqh, wkh, wvh);

  proj_gemm<2><<<dim3(128, 4), 256, 0, stream>>>(xh, wqh, bq, qsb);
  proj_gemm<2><<<dim3(128, 4), 256, 0, stream>>>(xh, wkh, bk, ksb);
  proj_gemm<1><<<dim3(4, 128), 256, 0, stream>>>(wvh, xh, bv, vtb);

  s_softmax<<<dim3(512), 256, 0, stream>>>(qsb, ksb, Pp, m_t, m_fin, l_hb);
  sm_merge<<<dim3(64), 256, 0, stream>>>(m_fin, l_hb, m_glb, l_fin);
  pv_gemm<<<dim3(1024), 256, 0, stream>>>(Pp, vtb, m_t, m_glb, l_fin,
                                          (float*)d_out);
}

// Round 20
// 177.703 us; speedup vs baseline: 1.2187x; 1.2187x over previous
//
#include <hip/hip_runtime.h>

// ---------------------------------------------------------------------------
// Fused QKV-projection + attention (B=8, C=2048, N=512), fp32 in/out.
// Round 20: EPILOGUE SOFTMAX (R19 post-mortem: inline online softmax put
// VALU+128 barriers on the K-loop critical path -> 104us. The m_t/sc scale
// numerics were validated though). New s_pmax = R18's proven s_gemm loop,
// then ONE epilogue pass: per-row max over the block's 128 cols (DPP +
// single cross-wn LDS exchange), P' = exp(S - m_blk) fp16 straight to memory
// (S fp32 never materialized), m_blk + tile row-sums out. sm_merge (tiny)
// builds m_glob, l_fin, and PRECOMPUTED sc = exp(m_t - m_glob). pv_gemm =
// R19's validated reg-staged-A kernel reading sc (no exp). softmax_rows and
// chunking deleted. Traffic vs R18: -250 MB. absmax expected bit-identical
// 3.356934e-3 (threshold 4.57e-3).
// ---------------------------------------------------------------------------

typedef _Float16 half_t;
typedef __attribute__((ext_vector_type(8))) _Float16 half8;
typedef __attribute__((ext_vector_type(4))) _Float16 half4;
typedef __attribute__((ext_vector_type(4))) float    f32x4;

#define MFMA16x32(A_, B_, C_) __builtin_amdgcn_mfma_f32_16x16x32_f16((A_), (B_), (C_), 0, 0, 0)

__device__ __forceinline__ void gload_lds16(const void* g, void* l) {
  __builtin_amdgcn_global_load_lds(
      (const __attribute__((address_space(1))) void*)g,
      (__attribute__((address_space(3))) void*)l, 16, 0, 0);
}

// 16-lane-group reductions via DPP (validated: R7+ max, R19 sum refcheck'd).
__device__ __forceinline__ float dpp_max16(float x) {
  int t;
  t = __builtin_amdgcn_update_dpp(__float_as_int(x), __float_as_int(x), 0xB1, 0xF, 0xF, false);
  x = fmaxf(x, __int_as_float(t));
  t = __builtin_amdgcn_update_dpp(__float_as_int(x), __float_as_int(x), 0x4E, 0xF, 0xF, false);
  x = fmaxf(x, __int_as_float(t));
  t = __builtin_amdgcn_update_dpp(__float_as_int(x), __float_as_int(x), 0x124, 0xF, 0xF, false);
  x = fmaxf(x, __int_as_float(t));
  t = __builtin_amdgcn_update_dpp(__float_as_int(x), __float_as_int(x), 0x128, 0xF, 0xF, false);
  x = fmaxf(x, __int_as_float(t));
  return x;
}
__device__ __forceinline__ float dpp_sum16(float x) {
  int t;
  t = __builtin_amdgcn_update_dpp(__float_as_int(x), __float_as_int(x), 0xB1, 0xF, 0xF, false);
  x += __int_as_float(t);
  t = __builtin_amdgcn_update_dpp(__float_as_int(x), __float_as_int(x), 0x4E, 0xF, 0xF, false);
  x += __int_as_float(t);
  t = __builtin_amdgcn_update_dpp(__float_as_int(x), __float_as_int(x), 0x124, 0xF, 0xF, false);
  x += __int_as_float(t);
  t = __builtin_amdgcn_update_dpp(__float_as_int(x), __float_as_int(x), 0x128, 0xF, 0xF, false);
  x += __int_as_float(t);
  return x;
}

// ---- merged cast: x + Wq + Wk + Wv in one launch ----------------------------
__global__ void cast_all(const float* __restrict__ x, const float* __restrict__ Wq,
                         const float* __restrict__ Wk, const float* __restrict__ Wv,
                         half_t* __restrict__ xh, half_t* __restrict__ wqh,
                         half_t* __restrict__ wkh, half_t* __restrict__ wvh) {
  int idx = blockIdx.x * 256 + threadIdx.x;   // float4 index
  const float* s;
  half_t* d;
  int off;
  if (idx < 2097152) { s = x; d = xh; off = idx; }
  else {
    int w = idx - 2097152;
    int which = w >> 16;
    off = w & 65535;
    s = (which == 0) ? Wq : (which == 1) ? Wk : Wv;
    d = (which == 0) ? wqh : (which == 1) ? wkh : wvh;
  }
  f32x4 v = ((const f32x4*)s)[off];
  half4 h;
#pragma unroll
  for (int j = 0; j < 4; ++j) h[j] = (_Float16)v[j];
  *(half4*)&d[(size_t)off * 4] = h;
}

// ---- GEMM core (R18, proven) ------------------------------------------------
template <int NKT, int SA, int SB, int MR>
__device__ __forceinline__ void gemm_core(
    const char* Abytes, const char* Bbytes,
    half_t* At, half_t* Bt, int tid, f32x4 (&acc)[MR][4]) {
  const int lane = tid & 63;
  const int wv = tid >> 6;
  const int g = lane >> 4, li = lane & 15;
  const int wm = wv >> 1, wn = wv & 1;
  const int ASTRIDE = MR * 2048;

  auto STAGE = [&](int kc, int buf) {
#pragma unroll
    for (int i2 = 0; i2 < MR; ++i2) {
      int seg = i2 * 256 + tid;
      int row = seg >> 3, blk = seg & 7;
      int bsrc = blk ^ (row & 7);
      gload_lds16(Abytes + ((size_t)row * SA + kc + bsrc * 8) * 2,
                  (void*)&At[buf * ASTRIDE + seg * 8]);
    }
#pragma unroll
    for (int i2 = 0; i2 < 4; ++i2) {
      int seg = i2 * 256 + tid;
      int row = seg >> 3, blk = seg & 7;
      int bsrc = blk ^ (row & 7);
      gload_lds16(Bbytes + ((size_t)row * SB + kc + bsrc * 8) * 2,
                  (void*)&Bt[buf * 8192 + seg * 8]);
    }
  };

  STAGE(0, 0);
  __syncthreads();
  int cur = 0;
#pragma unroll 1
  for (int kt = 0; kt < NKT; ++kt) {
    if (kt + 1 < NKT) STAGE((kt + 1) * 64, cur ^ 1);
#pragma unroll
    for (int kk = 0; kk < 2; ++kk) {
      half8 af[MR], bf[4];
#pragma unroll
      for (int i = 0; i < MR; ++i) {
        int ar = wm * (MR * 16) + i * 16 + li;
        af[i] = *(const half8*)&At[cur * ASTRIDE + ar * 64 + (((4 * kk + g) ^ (ar & 7)) * 8)];
      }
#pragma unroll
      for (int j = 0; j < 4; ++j) {
        int br = wn * 64 + j * 16 + li;
        bf[j] = *(const half8*)&Bt[cur * 8192 + br * 64 + (((4 * kk + g) ^ (br & 7)) * 8)];
      }
#pragma unroll
      for (int i = 0; i < MR; ++i)
#pragma unroll
        for (int j = 0; j < 4; ++j) acc[i][j] = MFMA16x32(af[i], bf[j], acc[i][j]);
    }
    __syncthreads();
    cur ^= 1;
  }
}

// ---- projection GEMM (unchanged) --------------------------------------------
// MODE 2: out[t*512 + m] (q/k compact); MODE 1: out[m*16384 + t] (v transposed)
template <int MODE>
__global__ __launch_bounds__(256) void proj_gemm(
    const half_t* __restrict__ A, const half_t* __restrict__ Bm,
    const float* __restrict__ bias, half_t* __restrict__ out) {
  __shared__ half_t At[2 * 4 * 2048];
  __shared__ half_t Bt[2 * 8192];
  const int tid = threadIdx.x;
  const int lane = tid & 63, wv = tid >> 6;
  const int g = lane >> 4, li = lane & 15;
  const int wm = wv >> 1, wn = wv & 1;
  const int M0 = blockIdx.x * 128, N0 = blockIdx.y * 128;

  const f32x4 kZero = {0.f, 0.f, 0.f, 0.f};
  f32x4 acc[4][4];
#pragma unroll
  for (int i = 0; i < 4; ++i)
#pragma unroll
    for (int j = 0; j < 4; ++j) acc[i][j] = kZero;

  gemm_core<8, 512, 512, 4>((const char*)(A + (size_t)M0 * 512),
                            (const char*)(Bm + (size_t)N0 * 512), At, Bt, tid, acc);

  if (MODE == 2) {
#pragma unroll
    for (int i = 0; i < 4; ++i) {
      int trow = M0 + wm * 64 + i * 16 + 4 * g;
#pragma unroll
      for (int j = 0; j < 4; ++j) {
        int m = N0 + wn * 64 + j * 16 + li;
        float bs = bias[m];
#pragma unroll
        for (int r = 0; r < 4; ++r) {
          out[(size_t)(trow + r) * 512 + m] = (_Float16)(acc[i][j][r] + bs);
        }
      }
    }
  } else {
#pragma unroll
    for (int i = 0; i < 4; ++i) {
      int m0r = M0 + wm * 64 + i * 16 + 4 * g;
#pragma unroll
      for (int r = 0; r < 4; ++r) {
        int m = m0r + r;
        float bs = bias[m];
#pragma unroll
        for (int j = 0; j < 4; ++j) {
          int t = N0 + wn * 64 + j * 16 + li;
          out[(size_t)m * 16384 + t] = (_Float16)(acc[i][j][r] + bs);
        }
      }
    }
  }
}

// ---- S-GEMM + epilogue blockwise softmax ------------------------------------
// grid 4096: b = id&7; idx = id>>3: M0 = (idx&31)*64 (c), N0 = (idx>>5)*128 (d).
// K-loop identical to R18 s_gemm (bit-identical S). Epilogue: per-row max over
// the block's 128 cols (DPP + cross-wn LDS), P' = exp(S-m_blk) fp16 out,
// m_t[row][tile] and l_t[row][tile] (tile = N0/128) out.
__global__ __launch_bounds__(256) void s_pmax(
    const half_t* __restrict__ q, const half_t* __restrict__ k,
    half_t* __restrict__ Pp, float* __restrict__ m_t, float* __restrict__ l_t) {
  __shared__ half_t At[2 * 2 * 2048];
  __shared__ half_t Bt[2 * 8192];
  __shared__ float  mx2[2][64];
  __shared__ float  sm2[2][64];
  const int tid = threadIdx.x;
  const int lane = tid & 63, wv = tid >> 6;
  const int g = lane >> 4, li = lane & 15;
  const int wm = wv >> 1, wn = wv & 1;
  const int id = blockIdx.x;
  const int b = id & 7;
  const int idx = id >> 3;
  const int M0 = (idx & 31) * 64;       // c-tile within batch
  const int N0 = (idx >> 5) * 128;      // d-tile
  const int tile = idx >> 5;            // 0..15

  const f32x4 kZero = {0.f, 0.f, 0.f, 0.f};
  f32x4 acc[2][4];
#pragma unroll
  for (int i = 0; i < 2; ++i)
#pragma unroll
    for (int j = 0; j < 4; ++j) acc[i][j] = kZero;

  gemm_core<8, 512, 512, 2>(
      (const char*)(q + (size_t)(b * 2048 + M0) * 512),
      (const char*)(k + (size_t)(b * 2048 + N0) * 512), At, Bt, tid, acc);

  // ---- epilogue: blockwise softmax over the 128 cols ----
  // local row index lr = wm*32 + i*16 + 4g + r; this lane's half = wn.
  float lmax[2][4];
#pragma unroll
  for (int i = 0; i < 2; ++i)
#pragma unroll
    for (int r = 0; r < 4; ++r) {
      float v = fmaxf(fmaxf(acc[0 + i][0][r], acc[i][1][r]),
                      fmaxf(acc[i][2][r], acc[i][3][r]));
      lmax[i][r] = dpp_max16(v);
    }
  if (li == 0) {
#pragma unroll
    for (int i = 0; i < 2; ++i)
#pragma unroll
      for (int r = 0; r < 4; ++r)
        mx2[wn][wm * 32 + i * 16 + 4 * g + r] = lmax[i][r];
  }
  __syncthreads();

  const size_t grow0 = (size_t)(b * 2048 + M0 + wm * 32);
  float tsum[2][4];
#pragma unroll
  for (int i = 0; i < 2; ++i) {
#pragma unroll
    for (int r = 0; r < 4; ++r) {
      int lr = wm * 32 + i * 16 + 4 * g + r;
      float m = fmaxf(mx2[0][lr], mx2[1][lr]);
      float s = 0.f;
#pragma unroll
      for (int j = 0; j < 4; ++j) {
        float p = __expf(acc[i][j][r] - m);
        s += p;
        Pp[(grow0 + i * 16 + 4 * g + r) * 2048 + N0 + wn * 64 + j * 16 + li] =
            (_Float16)p;
      }
      tsum[i][r] = dpp_sum16(s);
      lmax[i][r] = m;   // reuse as final m
    }
  }
  if (li == 0) {
#pragma unroll
    for (int i = 0; i < 2; ++i)
#pragma unroll
      for (int r = 0; r < 4; ++r)
        sm2[wn][wm * 32 + i * 16 + 4 * g + r] = tsum[i][r];
  }
  __syncthreads();
  if (wn == 0 && li == 0) {
#pragma unroll
    for (int i = 0; i < 2; ++i)
#pragma unroll
      for (int r = 0; r < 4; ++r) {
        int lr = wm * 32 + i * 16 + 4 * g + r;
        m_t[(grow0 + i * 16 + 4 * g + r) * 16 + tile] = lmax[i][r];
        l_t[(grow0 + i * 16 + 4 * g + r) * 16 + tile] = sm2[0][lr] + sm2[1][lr];
      }
  }
}

// ---- merge tiles: m_glob, l_fin, sc = exp(m_t - m_glob) ---------------------
__global__ void sm_merge(const float* __restrict__ m_t, const float* __restrict__ l_t,
                         float* __restrict__ sc_g, float* __restrict__ l_fin) {
  int rr = blockIdx.x * 256 + threadIdx.x;   // 0..16383
  float m[16];
  float mg = -3e38f;
#pragma unroll
  for (int t = 0; t < 16; ++t) { m[t] = m_t[rr * 16 + t]; mg = fmaxf(mg, m[t]); }
  float l = 0.f;
#pragma unroll
  for (int t = 0; t < 16; ++t) {
    float s = __expf(m[t] - mg);
    sc_g[rr * 16 + t] = s;
    l += l_t[rr * 16 + t] * s;
  }
  l_fin[rr] = l;
}

// ---- PV-GEMM (M=64): out[b][n][c] = (P . V^T) / (l * sqrt512) ---------------
// grid 1024: b = id&7; idx = id>>3: M0 = (idx>>2)*64, N0 = (idx&3)*128.
// A reg-staged from P' scaled by sc[row][kt>>1] (precomputed, LDS); B gload_lds.
__global__ __launch_bounds__(256) void pv_gemm(
    const half_t* __restrict__ Pp, const half_t* __restrict__ vt,
    const float* __restrict__ sc_g, const float* __restrict__ l_fin,
    float* __restrict__ outp) {
  __shared__ half_t At[2][2 * 2048];   // 2 x 8 KB (64 rows x 64 halves)
  __shared__ half_t Bt[2][8192];       // 2 x 16 KB
  __shared__ float  sc[64][17];        // per-(row, 128-tile) A scale
  const int tid = threadIdx.x;
  const int lane = tid & 63, wv = tid >> 6;
  const int g = lane >> 4, li = lane & 15;
  const int wm = wv >> 1, wn = wv & 1;
  const int id = blockIdx.x;
  const int b = id & 7;
  const int idx = id >> 3;
  const int M0 = (idx >> 2) * 64;      // c within batch
  const int N0 = (idx & 3) * 128;      // n
  const int rgb = b * 2048 + M0;

  // scales -> LDS (1024 entries, 4/thread)
#pragma unroll
  for (int i2 = 0; i2 < 4; ++i2) {
    int e = i2 * 256 + tid;
    int row = e >> 4, t = e & 15;
    sc[row][t] = sc_g[(size_t)(rgb + row) * 16 + t];
  }

  const half_t* Pb = Pp + (size_t)rgb * 2048;
  const char* Bb = (const char*)(vt + (size_t)N0 * 16384 + (size_t)b * 2048);

  auto BSTAGE = [&](int kt, int buf) {
#pragma unroll
    for (int i2 = 0; i2 < 4; ++i2) {
      int seg = i2 * 256 + tid;
      int row = seg >> 3, blk = seg & 7;
      int bsrc = blk ^ (row & 7);
      gload_lds16(Bb + ((size_t)row * 16384 + kt * 64 + bsrc * 8) * 2,
                  (void*)&Bt[buf][seg * 8]);
    }
  };
  const int s0row = tid >> 3, s0blk = tid & 7;
  const int s1row = (256 + tid) >> 3, s1blk = tid & 7;

  __syncthreads();   // sc visible

  half8 a0 = *(const half8*)&Pb[(size_t)s0row * 2048 + s0blk * 8];
  half8 a1 = *(const half8*)&Pb[(size_t)s1row * 2048 + s1blk * 8];
  BSTAGE(0, 0);
  {
    _Float16 f0 = (_Float16)sc[s0row][0], f1 = (_Float16)sc[s1row][0];
#pragma unroll
    for (int e = 0; e < 8; ++e) { a0[e] *= f0; a1[e] *= f1; }
    *(half8*)&At[0][s0row * 64 + ((s0blk ^ (s0row & 7)) * 8)] = a0;
    *(half8*)&At[0][s1row * 64 + ((s1blk ^ (s1row & 7)) * 8)] = a1;
  }
  __syncthreads();

  const f32x4 kZero = {0.f, 0.f, 0.f, 0.f};
  f32x4 acc[2][4];
#pragma unroll
  for (int i = 0; i < 2; ++i)
#pragma unroll
    for (int j = 0; j < 4; ++j) acc[i][j] = kZero;

  int cur = 0;
#pragma unroll 1
  for (int kt = 0; kt < 32; ++kt) {
    half8 n0, n1;
    if (kt + 1 < 32) {
      n0 = *(const half8*)&Pb[(size_t)s0row * 2048 + (kt + 1) * 64 + s0blk * 8];
      n1 = *(const half8*)&Pb[(size_t)s1row * 2048 + (kt + 1) * 64 + s1blk * 8];
      BSTAGE(kt + 1, cur ^ 1);
    }
#pragma unroll
    for (int kk = 0; kk < 2; ++kk) {
      half8 af[2], bf[4];
#pragma unroll
      for (int i = 0; i < 2; ++i) {
        int arr = wm * 32 + i * 16 + li;
        af[i] = *(const half8*)&At[cur][arr * 64 + (((4 * kk + g) ^ (arr & 7)) * 8)];
      }
#pragma unroll
      for (int j = 0; j < 4; ++j) {
        int br = wn * 64 + j * 16 + li;
        bf[j] = *(const half8*)&Bt[cur][br * 64 + (((4 * kk + g) ^ (br & 7)) * 8)];
      }
#pragma unroll
      for (int i = 0; i < 2; ++i)
#pragma unroll
        for (int j = 0; j < 4; ++j) acc[i][j] = MFMA16x32(af[i], bf[j], acc[i][j]);
    }
    if (kt + 1 < 32) {
      _Float16 f0 = (_Float16)sc[s0row][(kt + 1) >> 1];
      _Float16 f1 = (_Float16)sc[s1row][(kt + 1) >> 1];
#pragma unroll
      for (int e = 0; e < 8; ++e) { n0[e] *= f0; n1[e] *= f1; }
      *(half8*)&At[cur ^ 1][s0row * 64 + ((s0blk ^ (s0row & 7)) * 8)] = n0;
      *(half8*)&At[cur ^ 1][s1row * 64 + ((s1blk ^ (s1row & 7)) * 8)] = n1;
    }
    __syncthreads();
    cur ^= 1;
  }

  // epilogue: 1/(l*sqrt(512)), transposed scatter out[b][n][c]
#pragma unroll
  for (int i = 0; i < 2; ++i) {
    int c0r = M0 + wm * 32 + i * 16 + 4 * g;
    float inv[4];
#pragma unroll
    for (int r = 0; r < 4; ++r)
      inv[r] = 1.0f / (l_fin[b * 2048 + c0r + r] * 22.62741699796952f);
#pragma unroll
    for (int j = 0; j < 4; ++j) {
      int n = N0 + wn * 64 + j * 16 + li;
      float* ob = outp + (size_t)b * 1048576 + (size_t)n * 2048 + c0r;
#pragma unroll
      for (int r = 0; r < 4; ++r) {
        ob[r] = acc[i][j][r] * inv[r];
      }
    }
  }
}

// ---------------------------------------------------------------------------
extern "C" void kernel_launch(void* const* d_in, const int* in_sizes, int n_in,
                              void* d_out, int out_size, void* d_ws, size_t ws_size,
                              hipStream_t stream) {
  const float* x  = (const float*)d_in[0];
  const float* Wq = (const float*)d_in[1];
  const float* bq = (const float*)d_in[2];
  const float* Wk = (const float*)d_in[3];
  const float* bk = (const float*)d_in[4];
  const float* Wv = (const float*)d_in[5];
  const float* bv = (const float*)d_in[6];

  // workspace layout:
  half_t* qsb  = (half_t*)d_ws;                     // [16384][512]   16 MB
  half_t* ksb  = qsb + (size_t)16384 * 512;         // [16384][512]   16 MB
  half_t* vtb  = ksb + (size_t)16384 * 512;         // [512][16384]   16 MB
  half_t* Pp   = vtb + (size_t)512 * 16384;         // [16384][2048]  67 MB (attn)
  half_t* xh   = Pp;                                // [16384][512]   (proj phase)
  half_t* wqh  = xh  + (size_t)16384 * 512;
  half_t* wkh  = wqh + (size_t)512 * 512;
  half_t* wvh  = wkh + (size_t)512 * 512;
  float*  m_t  = (float*)(Pp + (size_t)16384 * 2048);   // [16384][16]  1 MB
  float*  l_t  = m_t + (size_t)16384 * 16;              // [16384][16]  1 MB
  float*  sc_g = l_t + (size_t)16384 * 16;              // [16384][16]  1 MB
  float*  l_fin = sc_g + (size_t)16384 * 16;            // [16384]

  cast_all<<<dim3(8960), 256, 0, stream>>>(x, Wq, Wk, Wv, xh, wqh, wkh, wvh);

  proj_gemm<2><<<dim3(128, 4), 256, 0, stream>>>(xh, wqh, bq, qsb);
  proj_gemm<2><<<dim3(128, 4), 256, 0, stream>>>(xh, wkh, bk, ksb);
  proj_gemm<1><<<dim3(4, 128), 256, 0, stream>>>(wvh, xh, bv, vtb);

  s_pmax<<<dim3(4096), 256, 0, stream>>>(qsb, ksb, Pp, m_t, l_t);
  sm_merge<<<dim3(64), 256, 0, stream>>>(m_t, l_t, sc_g, l_fin);
  pv_gemm<<<dim3(1024), 256, 0, stream>>>(Pp, vtb, sc_g, l_fin, (float*)d_out);
}